// Round 15
// baseline (333.224 us; speedup 1.0000x reference)
//
#include <hip/hip_runtime.h>

typedef __attribute__((ext_vector_type(8))) unsigned short u16x8;
typedef __attribute__((ext_vector_type(8))) short s16x8;
typedef __attribute__((ext_vector_type(4))) float f32x4;

#define NPTS 400000
#define HW 32400
#define WID 180
#define NCI 256
#define NCO 64
#define NSEG 2560
#define NINST 256
#define NBLK 500
#define PPB 800    // NBLK * PPB = 400000

__device__ __forceinline__ float bf2f(unsigned short u) {
  union { unsigned int i; float f; } v; v.i = ((unsigned int)u) << 16; return v.f;
}
__device__ __forceinline__ unsigned short f2bf(float f) {
  unsigned int u = __float_as_uint(f);
  return (unsigned short)((u + 0x7fffu + ((u >> 16) & 1u)) >> 16);
}

__device__ __forceinline__ void gld_lds16(const void* g, void* l) {
  __builtin_amdgcn_global_load_lds((const __attribute__((address_space(1))) void*)g,
                                   (__attribute__((address_space(3))) void*)l, 16, 0, 0);
}

// ---------------- K0: NCHW fp32 -> NHWC bf16 transpose ----------------
// Column-block XOR swizzle (ci ^ (row&3)<<3) fixes the 8-way write conflict;
// reads apply the same XOR on the 8-float block index (stays 16B-aligned).
__global__ __launch_bounds__(256) void k_transpose(const float* __restrict__ x,
                                                   unsigned short* __restrict__ xt) {
  const int bw = blockIdx.x;            // wtile = bw>>2 (0..2), citile = bw&3
  const int h = blockIdx.y, b = blockIdx.z;
  const int w0 = (bw >> 2) * 64, ci0 = (bw & 3) * 64;
  __shared__ float tile[64][68];
  const int t = threadIdx.x;
  const int a = t & 15, c4 = t >> 4;
  const int w4 = a * 4;
  const bool ldok = (w0 + w4) < WID;    // w0=128 tail: 52%4==0, no partial vectors
#pragma unroll
  for (int it = 0; it < 4; ++it) {
    int ci = c4 + it * 16;
    float4 v = make_float4(0.f, 0.f, 0.f, 0.f);
    if (ldok) v = *(const float4*)(x + ((size_t)(b * NCI + ci0 + ci) * WID + h) * WID + w0 + w4);
    tile[w4 + 0][ci ^ 0]  = v.x;
    tile[w4 + 1][ci ^ 8]  = v.y;
    tile[w4 + 2][ci ^ 16] = v.z;
    tile[w4 + 3][ci ^ 24] = v.w;
  }
  __syncthreads();
  const int q = t & 7, r = t >> 3;
#pragma unroll
  for (int it = 0; it < 2; ++it) {
    int wl = r + it * 32;
    int w = w0 + wl;
    if (w >= WID) continue;
    const float* row = &tile[wl][(q ^ (wl & 3)) * 8];
    float4 lo = *(const float4*)(row);
    float4 hi = *(const float4*)(row + 4);
    u16x8 o;
    o[0] = f2bf(lo.x); o[1] = f2bf(lo.y); o[2] = f2bf(lo.z); o[3] = f2bf(lo.w);
    o[4] = f2bf(hi.x); o[5] = f2bf(hi.y); o[6] = f2bf(hi.z); o[7] = f2bf(hi.w);
    *(u16x8*)(xt + ((size_t)((b * WID + h) * WID + w)) * NCI + ci0 + q * 8) = o;
  }
}

// ---------------- K0b: conv_w -> wb[tap][chunk][co][32ci] bf16 ----------------
__global__ void k_wreorg(const float* __restrict__ wt, unsigned short* __restrict__ wb) {
  int id = blockIdx.x * 256 + threadIdx.x;
  if (id >= 9 * 8 * 64 * 32) return;
  int cw = id & 31;
  int co = (id >> 5) & 63;
  int chunk = (id >> 11) & 7;
  int tap = id >> 14;
  int ci = chunk * 32 + cw;
  wb[id] = f2bf(wt[((size_t)co * 256 + ci) * 9 + tap]);
}

// ---------------- K1: implicit-GEMM conv, M=192, 3-buffer counted-vmcnt pipeline ----------------
#define ROWB 6272       // 98 * 64
#define RBUF 26624      // 25 real rows (25600) + 1KB dummy row for uniform stage counts
__global__ __launch_bounds__(256, 2) void k_conv_mfma(const unsigned short* __restrict__ xt,
                                                   const unsigned short* __restrict__ wb,
                                                   const float* __restrict__ zbuf,
                                                   unsigned short* __restrict__ y,
                                                   float* __restrict__ part) {
  const int wg = blockIdx.x;                    // 0..719
  const int lin = (wg & 7) * 90 + (wg >> 3);    // bijective: 720 = 8*90
  const int h2 = lin % 90;
  const int t2 = lin / 90;                      // b*2 + wth
  const int wth = t2 & 1, b = t2 >> 1;
  const int h0 = h2 * 2;
  const int w0 = wth * 96;
  __shared__ unsigned char strip[3][RBUF];
  __shared__ float redS[2][2][2][16], redQ[2][2][2][16]; // [mh][nh][nf][l15]
  const int tid = threadIdx.x;
  const int lane = tid & 63, wv = tid >> 6;
  const int mh = wv >> 1, nh = wv & 1;
  const int l15 = lane & 15, lk = lane >> 4;

  // per-lane pre-swizzled global sources; uniform 7 loads/wave (invalid -> zbuf, dummy row 25)
  const char* srcs[7];
  int dstrow[7];
#pragma unroll
  for (int k = 0; k < 7; ++k) {
    int j = wv + k * 4;
    int g = j * 64 + lane;          // 16B-unit index
    int pxlin = g >> 2, sub = g & 3;
    int row = pxlin / 98;
    int px = pxlin - row * 98;
    int hh = h0 + row - 1;
    int worig = w0 + px - 1;
    bool valid = (j < 25) && (pxlin < 392) &&
                 (hh >= 0) && (hh < WID) && (worig >= 0) && (worig < WID);
    int cig = sub ^ ((px >> 1) & 3);
    srcs[k] = valid
        ? (const char*)(xt + ((size_t)((b * WID + hh) * WID + worig)) * NCI + cig * 8)
        : (const char*)zbuf + lane * 16;   // +chunk*64 stays inside 2KB
    dstrow[k] = (j < 25) ? j : 25;         // dummy row keeps 7 loads on every wave
  }

  f32x4 acc[6][2];
#pragma unroll
  for (int i = 0; i < 6; ++i)
#pragma unroll
    for (int j = 0; j < 2; ++j) { acc[i][j][0] = 0.f; acc[i][j][1] = 0.f; acc[i][j][2] = 0.f; acc[i][j][3] = 0.f; }

  auto stage = [&](unsigned char* buf, int chunk) {
#pragma unroll
    for (int k = 0; k < 7; ++k)
      gld_lds16(srcs[k] + chunk * 64, buf + dstrow[k] * 1024);
  };

  stage(strip[0], 0);
  stage(strip[1], 1);
  asm volatile("s_waitcnt vmcnt(7)" ::: "memory");   // buf0 landed; buf1's 7 may fly
  __builtin_amdgcn_s_barrier();
  __builtin_amdgcn_sched_barrier(0);

  const unsigned short* wco[2];
#pragma unroll
  for (int nf = 0; nf < 2; ++nf)
    wco[nf] = wb + (size_t)((nh * 2 + nf) * 16 + l15) * 32 + lk * 8;

  for (int chunk = 0; chunk < 8; ++chunk) {
    s16x8 bfr[9][2];
#pragma unroll
    for (int tap = 0; tap < 9; ++tap)
#pragma unroll
      for (int nf = 0; nf < 2; ++nf)
        bfr[tap][nf] = *(const s16x8*)(wco[nf] + (size_t)(tap * 8 + chunk) * 2048);
    if (chunk < 6) stage(strip[(chunk + 2) % 3], chunk + 2);
    const unsigned char* buf = strip[chunk % 3];
#pragma unroll
    for (int tap = 0; tap < 9; ++tap) {
      const int dh = tap / 3, dw = tap % 3;
      s16x8 afr[6];
#pragma unroll
      for (int i = 0; i < 6; ++i) {
        int wp = i * 16 + l15 + dw;
        int byte = (mh + dh) * ROWB + wp * 64 + ((lk ^ ((wp >> 1) & 3)) * 16);
        afr[i] = *(const s16x8*)(buf + byte);
      }
#pragma unroll
      for (int i = 0; i < 6; ++i)
#pragma unroll
        for (int nf = 0; nf < 2; ++nf)
          acc[i][nf] = __builtin_amdgcn_mfma_f32_16x16x32_bf16(afr[i], bfr[tap][nf], acc[i][nf], 0, 0, 0);
    }
    // counted wait: only next-next stage (7 loads) may stay in flight.
    // stage(chunk+1) is older than this chunk's consumed weights -> already retired.
    asm volatile("s_waitcnt vmcnt(7) lgkmcnt(0)" ::: "memory");
    __builtin_amdgcn_s_barrier();
    __builtin_amdgcn_sched_barrier(0);
  }

  // epilogue: y store + per-channel partial BN stats (valid pixels only)
  const int r4 = lk * 4;
  const int hrow = h0 + mh;
  float s[2] = {0.f, 0.f}, q[2] = {0.f, 0.f};
#pragma unroll
  for (int i = 0; i < 6; ++i) {
#pragma unroll
    for (int nf = 0; nf < 2; ++nf) {
      int co = (nh * 2 + nf) * 16 + l15;
#pragma unroll
      for (int j = 0; j < 4; ++j) {
        int w = w0 + i * 16 + r4 + j;
        if (w < WID) {
          float v = acc[i][nf][j];
          y[((size_t)(b * HW) + hrow * WID + w) * 64 + co] = f2bf(v);
          s[nf] += v; q[nf] = fmaf(v, v, q[nf]);
        }
      }
    }
  }
#pragma unroll
  for (int nf = 0; nf < 2; ++nf) {
    s[nf] += __shfl_xor(s[nf], 16); s[nf] += __shfl_xor(s[nf], 32);
    q[nf] += __shfl_xor(q[nf], 16); q[nf] += __shfl_xor(q[nf], 32);
  }
  if (lk == 0) {
#pragma unroll
    for (int nf = 0; nf < 2; ++nf) { redS[mh][nh][nf][l15] = s[nf]; redQ[mh][nh][nf][l15] = q[nf]; }
  }
  __syncthreads();
  if (tid < 64) {
    int co = tid;
    int nhh = co >> 5, nff = (co >> 4) & 1, ll = co & 15;
    part[((size_t)wg * 64 + co) * 2 + 0] = redS[0][nhh][nff][ll] + redS[1][nhh][nff][ll];
    part[((size_t)wg * 64 + co) * 2 + 1] = redQ[0][nhh][nff][ll] + redQ[1][nhh][nff][ll];
  }
}

// ---------------- K2b: final BN scale/shift from 720 partials (4-way parallel) ----------------
__global__ void k_bnparams(const float* __restrict__ part, const float* __restrict__ gamma,
                           const float* __restrict__ beta, float* __restrict__ ab) {
  __shared__ float ls[256], lss[256];
  const int t = threadIdx.x;            // 256
  const int c = t & 63, g = t >> 6;     // 4 groups per channel
  float s = 0.f, ss = 0.f;
  for (int k = g; k < 720; k += 4) {
    s += part[((size_t)k * 64 + c) * 2];
    ss += part[((size_t)k * 64 + c) * 2 + 1];
  }
  ls[t] = s; lss[t] = ss;
  __syncthreads();
  if (t < 64) {
    s = ls[t] + ls[t + 64] + ls[t + 128] + ls[t + 192];
    ss = lss[t] + lss[t + 64] + lss[t + 128] + lss[t + 192];
    float mu = s / 129600.f;
    float var = ss / 129600.f - mu * mu;
    float a = rsqrtf(var + 1e-5f) * gamma[t];
    ab[t * 2] = a; ab[t * 2 + 1] = beta[t] - mu * a;
  }
}

// ---------------- K4: bilinear gather with fused BN+ReLU, 8 points/wave ----------------
__global__ __launch_bounds__(256) void k_points(const float* __restrict__ pts,
                         const unsigned short* __restrict__ y,
                         const float* __restrict__ ab,
                         unsigned short* __restrict__ pf) {
  const int gid = blockIdx.x * 256 + threadIdx.x;
  const int lane = gid & 63;
  const int wid = gid >> 6;
  const float sa = ab[lane * 2], sb = ab[lane * 2 + 1];
#pragma unroll
  for (int it = 0; it < 8; ++it) {
    int p = wid * 8 + it;  // 12500 blocks * 4 waves * 8 = 400000
    const float* pr = pts + (size_t)p * 9;
    float pbf = pr[0], xx = pr[1], yy = pr[2];
    int b = (int)pbf;
    float px = (xx - (-54.0f)) / 0.6f;
    float py = (yy - (-54.0f)) / 0.6f;
    int x0 = (int)floorf(px); x0 = min(max(x0, 0), WID - 1);
    int x1 = min(x0 + 1, WID - 1);
    int y0 = (int)floorf(py); y0 = min(max(y0, 0), WID - 1);
    int y1 = min(y0 + 1, WID - 1);
    float x0f = (float)x0, x1f = (float)x1, y0f = (float)y0, y1f = (float)y1;
    float wa = (x1f - px) * (y1f - py);
    float wb = (x1f - px) * (py - y0f);
    float wc = (px - x0f) * (y1f - py);
    float wd = (px - x0f) * (py - y0f);
    int i00 = y0 * WID + x0;
    int dx = x1 - x0;
    int dy = (y1 - y0) * WID;
    const unsigned short* bb = y + ((size_t)b * HW) * 64 + lane;
    float Ia = fmaf(bf2f(bb[(size_t)i00 * 64]), sa, sb);             Ia = Ia > 0.f ? Ia : 0.f;
    float Ic = fmaf(bf2f(bb[(size_t)(i00 + dx) * 64]), sa, sb);      Ic = Ic > 0.f ? Ic : 0.f;
    float Ib = fmaf(bf2f(bb[(size_t)(i00 + dy) * 64]), sa, sb);      Ib = Ib > 0.f ? Ib : 0.f;
    float Id = fmaf(bf2f(bb[(size_t)(i00 + dy + dx) * 64]), sa, sb); Id = Id > 0.f ? Id : 0.f;
    float f = wa * Ia + wb * Ib + wc * Ic + wd * Id;
    pf[(size_t)p * 64 + lane] = f2bf(f);
  }
}

// ---------------- K4b: point heads (cls/offset/embedding), vectorized pf reads ----------------
__global__ void k_heads(const unsigned short* __restrict__ pf,
                        const float* __restrict__ wseg, const float* __restrict__ bseg,
                        const float* __restrict__ wreg, const float* __restrict__ breg,
                        const float* __restrict__ wemb, const float* __restrict__ bemb,
                        float* __restrict__ ocls, float* __restrict__ ooff, float* __restrict__ oemb) {
  const int p = blockIdx.x * 256 + threadIdx.x;
  if (p >= NPTS) return;
  float a0 = bseg[0], a1 = bseg[1], a2 = bseg[2];
  float r0 = breg[0], r1 = breg[1], r2 = breg[2];
  float e0 = bemb[0], e1 = bemb[1];
  const u16x8* q = (const u16x8*)(pf + (size_t)p * 64);
#pragma unroll
  for (int g = 0; g < 8; ++g) {
    u16x8 v8 = q[g];
#pragma unroll
    for (int k = 0; k < 8; ++k) {
      int kk = g * 8 + k;
      float v = bf2f(v8[k]);
      a0 = fmaf(v, wseg[kk * 3 + 0], a0);
      a1 = fmaf(v, wseg[kk * 3 + 1], a1);
      a2 = fmaf(v, wseg[kk * 3 + 2], a2);
      r0 = fmaf(v, wreg[kk * 3 + 0], r0);
      r1 = fmaf(v, wreg[kk * 3 + 1], r1);
      r2 = fmaf(v, wreg[kk * 3 + 2], r2);
      e0 = fmaf(v, wemb[kk * 2 + 0], e0);
      e1 = fmaf(v, wemb[kk * 2 + 1], e1);
    }
  }
  ocls[p * 3 + 0] = a0; ocls[p * 3 + 1] = a1; ocls[p * 3 + 2] = a2;
  ooff[p * 3 + 0] = r0; ooff[p * 3 + 1] = r1; ooff[p * 3 + 2] = r2;
  oemb[p * 2 + 0] = e0; oemb[p * 2 + 1] = e1;
}

// ---------------- K5: LDS-privatized histogram + local rank (coalesced [blk][seg] writeback) ----------------
__global__ __launch_bounds__(256) void k_hist2(const float* __restrict__ pts,
                                               int* __restrict__ seg, int* __restrict__ rankp,
                                               int* __restrict__ bh) {
  __shared__ int lc[NSEG];
  const int t = threadIdx.x, blk = blockIdx.x;
  for (int i = t; i < NSEG; i += 256) lc[i] = 0;
  __syncthreads();
  const int p0 = blk * PPB;
  for (int i = t; i < PPB; i += 256) {
    int p = p0 + i;
    const float* pr = pts + (size_t)p * 9;
    int b = (int)pr[0];
    int sw = (int)pr[6];
    int ins = (int)pr[7];
    int s = (b * 64 + ins) * 10 + sw;
    seg[p] = s;
    rankp[p] = atomicAdd(&lc[s], 1);
  }
  __syncthreads();
  for (int i = t; i < NSEG; i += 256) bh[(size_t)blk * NSEG + i] = lc[i];
}

// ---------------- K6a: per-segment prefix across blocks (coalesced row sweeps) ----------------
__global__ void k_scan2a(const int* __restrict__ bh, int* __restrict__ basebk,
                         int* __restrict__ tot) {
  const int s = blockIdx.x * 256 + threadIdx.x;  // 0..2559
  int acc = 0;
  for (int b = 0; b < NBLK; ++b) {
    int v = bh[(size_t)b * NSEG + s];
    basebk[(size_t)b * NSEG + s] = acc;
    acc += v;
  }
  tot[s] = acc;
}

// ---------------- K6b: exclusive scan of segment totals ----------------
__global__ void k_scan2b(const int* __restrict__ tot, int* __restrict__ base,
                         int* __restrict__ cnt) {
  __shared__ int csum[256];
  const int t = threadIdx.x;
  int loc[10]; int run = 0;
#pragma unroll
  for (int k = 0; k < 10; ++k) { loc[k] = tot[t * 10 + k]; run += loc[k]; }
  csum[t] = run;
  __syncthreads();
  if (t == 0) {
    int a = 0;
    for (int i = 0; i < 256; ++i) { int v = csum[i]; csum[i] = a; a += v; }
  }
  __syncthreads();
  int acc = csum[t];
#pragma unroll
  for (int k = 0; k < 10; ++k) {
    int s = t * 10 + k;
    base[s] = acc; cnt[s] = loc[k];
    acc += loc[k];
  }
}

// ---------------- K7: atomic-free scatter ----------------
__global__ void k_scatter2(const int* __restrict__ seg, const int* __restrict__ rankp,
                           const int* __restrict__ base, const int* __restrict__ basebk,
                           int* __restrict__ order) {
  const int p = blockIdx.x * 256 + threadIdx.x;
  if (p < NPTS) {
    int s = seg[p];
    int blk = p / PPB;
    order[base[s] + basebk[(size_t)blk * NSEG + s] + rankp[p]] = p;
  }
}

// ---------------- K8: per-segment centroid + shape max + feat max (8 waves) ----------------
__global__ __launch_bounds__(512) void k_seg(const int* __restrict__ cnt, const int* __restrict__ base,
                      const int* __restrict__ order, const float* __restrict__ pts,
                      const unsigned short* __restrict__ pf,
                      const float* __restrict__ wsh, const float* __restrict__ bsh,
                      float* __restrict__ lf, float* __restrict__ centroid,
                      int* __restrict__ nonempty) {
  const int s = blockIdx.x;
  const int t = threadIdx.x, lane = t & 63, wv = t >> 6;
  const int n = cnt[s], bs = base[s];
  float sx = 0.f, sy = 0.f, sz = 0.f;
  for (int i = t; i < n; i += 512) {
    int p = order[bs + i];
    const float* pr = pts + (size_t)p * 9;
    sx += pr[1]; sy += pr[2]; sz += pr[3];
  }
#pragma unroll
  for (int m = 32; m > 0; m >>= 1) {
    sx += __shfl_xor(sx, m); sy += __shfl_xor(sy, m); sz += __shfl_xor(sz, m);
  }
  __shared__ float red[3][8];
  __shared__ float csh[3];
  if (lane == 0) { red[0][wv] = sx; red[1][wv] = sy; red[2][wv] = sz; }
  __syncthreads();
  if (t == 0) {
    float dn = (float)max(n, 1);
    float ax = 0.f, ay = 0.f, az = 0.f;
#pragma unroll
    for (int k = 0; k < 8; ++k) { ax += red[0][k]; ay += red[1][k]; az += red[2][k]; }
    csh[0] = ax / dn; csh[1] = ay / dn; csh[2] = az / dn;
  }
  __syncthreads();
  const float cx = csh[0], cy = csh[1], cz = csh[2];
  const float w0 = wsh[lane], w1 = wsh[64 + lane], w2 = wsh[128 + lane], bb = bsh[lane];
  float smax = -INFINITY, lmax = -INFINITY;
  for (int i = wv; i < n; i += 8) {
    int p = order[bs + i];
    const float* pr = pts + (size_t)p * 9;
    float sv = fmaf(pr[1] - cx, w0, fmaf(pr[2] - cy, w1, fmaf(pr[3] - cz, w2, bb)));
    smax = fmaxf(smax, sv);
    lmax = fmaxf(lmax, bf2f(pf[(size_t)p * 64 + lane]));
  }
  __shared__ float rs[8][64], rl[8][64];
  rs[wv][lane] = smax; rl[wv][lane] = lmax;
  __syncthreads();
  if (wv == 0) {
#pragma unroll
    for (int k = 1; k < 8; ++k) {
      smax = fmaxf(smax, rs[k][lane]);
      lmax = fmaxf(lmax, rl[k][lane]);
    }
    bool ne = n > 0;
    lf[s * 64 + lane] = (ne ? lmax : 0.f) + (ne ? smax : 0.f);
    if (lane == 0) {
      nonempty[s] = ne ? 1 : 0;
      centroid[s * 3 + 0] = cx; centroid[s * 3 + 1] = cy; centroid[s * 3 + 2] = cz;
    }
  }
}

// ---------------- K9: per-instance globals + sweep min/max + inst_mos ----------------
__global__ void k_glob(const float* __restrict__ lf, const int* __restrict__ ne,
                       const float* __restrict__ centroid,
                       const float* __restrict__ wmos, const float* __restrict__ bmos,
                       float* __restrict__ gf, float* __restrict__ tc, float* __restrict__ ic,
                       float* __restrict__ omos) {
  const int i = blockIdx.x;
  const int t = threadIdx.x; // 64 threads
  float g = -INFINITY;
  int maxsw = -1, minsw = 10;
  bool any = false;
#pragma unroll
  for (int s = 0; s < 10; ++s) {
    int idx = i * 10 + s;
    bool e = ne[idx] != 0;
    float v = lf[idx * 64 + t];
    g = fmaxf(g, e ? v : -INFINITY);
    if (e) { any = true; maxsw = s; minsw = min(minsw, s); }
  }
  float gv = any ? g : 0.f;
  gf[i * 64 + t] = gv;
  int idxmax = min(max(i * 10 + maxsw, 0), NSEG - 1);
  int idxmin = min(max(i * 10 + minsw, 0), NSEG - 1);
  float tcx = centroid[idxmax * 3 + 0], tcy = centroid[idxmax * 3 + 1], tcz = centroid[idxmax * 3 + 2];
  float icx = centroid[idxmin * 3 + 0], icy = centroid[idxmin * 3 + 1], icz = centroid[idxmin * 3 + 2];
  if (t == 0) {
    tc[i * 3 + 0] = tcx; tc[i * 3 + 1] = tcy; tc[i * 3 + 2] = tcz;
    ic[i * 3 + 0] = icx; ic[i * 3 + 1] = icy; ic[i * 3 + 2] = icz;
  }
  float r = gv * wmos[t];
#pragma unroll
  for (int m = 32; m > 0; m >>= 1) r += __shfl_xor(r, m);
  if (t == 0) {
    r += icx * wmos[64] + icy * wmos[65] + icz * wmos[66];
    r += tcx * wmos[67] + tcy * wmos[68] + tcz * wmos[69];
    omos[i] = r + bmos[0];
  }
}

// ---------------- K10: locals_tf = locals_cat(134) @ w_tf(134x7) ----------------
__global__ void k_tf(const float* __restrict__ lf, const float* __restrict__ gf,
                     const float* __restrict__ centroid, const float* __restrict__ tc,
                     const float* __restrict__ wtf, const float* __restrict__ btf,
                     float* __restrict__ otf) {
  const int r = blockIdx.x * 256 + threadIdx.x;
  if (r >= NSEG) return;
  const int i = r / 10;
  float acc[7];
#pragma unroll
  for (int j = 0; j < 7; ++j) acc[j] = btf[j];
  for (int k = 0; k < 64; ++k) {
    float v = lf[r * 64 + k];
#pragma unroll
    for (int j = 0; j < 7; ++j) acc[j] = fmaf(v, wtf[k * 7 + j], acc[j]);
  }
  for (int k = 0; k < 64; ++k) {
    float v = gf[i * 64 + k];
#pragma unroll
    for (int j = 0; j < 7; ++j) acc[j] = fmaf(v, wtf[(64 + k) * 7 + j], acc[j]);
  }
#pragma unroll
  for (int c = 0; c < 3; ++c) {
    float v = centroid[r * 3 + c];
#pragma unroll
    for (int j = 0; j < 7; ++j) acc[j] = fmaf(v, wtf[(128 + c) * 7 + j], acc[j]);
  }
#pragma unroll
  for (int c = 0; c < 3; ++c) {
    float v = tc[i * 3 + c];
#pragma unroll
    for (int j = 0; j < 7; ++j) acc[j] = fmaf(v, wtf[(131 + c) * 7 + j], acc[j]);
  }
#pragma unroll
  for (int j = 0; j < 7; ++j) otf[r * 7 + j] = acc[j];
}

extern "C" void kernel_launch(void* const* d_in, const int* in_sizes, int n_in,
                              void* d_out, int out_size, void* d_ws, size_t ws_size,
                              hipStream_t stream) {
  const float* pts   = (const float*)d_in[0];
  const float* x     = (const float*)d_in[1];
  const float* convw = (const float*)d_in[2];
  const float* gamma = (const float*)d_in[3];
  const float* beta  = (const float*)d_in[4];
  const float* wseg  = (const float*)d_in[5];
  const float* bseg  = (const float*)d_in[6];
  const float* wreg  = (const float*)d_in[7];
  const float* breg  = (const float*)d_in[8];
  const float* wemb  = (const float*)d_in[9];
  const float* bemb  = (const float*)d_in[10];
  const float* wsh   = (const float*)d_in[11];
  const float* bsh   = (const float*)d_in[12];
  const float* wtf   = (const float*)d_in[13];
  const float* btf   = (const float*)d_in[14];
  const float* wmos  = (const float*)d_in[15];
  const float* bmos  = (const float*)d_in[16];

  float* out = (float*)d_out;
  float* o_cls = out;                 // 400000 x 3
  float* o_off = out + 1200000;       // 400000 x 3
  float* o_emb = out + 2400000;       // 400000 x 2
  float* o_tf  = out + 3200000;       // 2560 x 7
  float* o_mos = out + 3217920;       // 256 x 1

  char* wsp = (char*)d_ws;
  size_t off = 0;
  auto alloc = [&](size_t bytes) -> void* {
    void* p = wsp + off;
    off = (off + bytes + 255) & ~(size_t)255;
    return p;
  };
  // xt dead after conv -> pf aliases it.
  unsigned short* xt   = (unsigned short*)alloc((size_t)4 * WID * WID * NCI * 2); // 66.4 MB
  unsigned short* pf   = xt;
  unsigned short* wbuf = (unsigned short*)alloc((size_t)9 * 8 * 64 * 32 * 2);
  unsigned short* y    = (unsigned short*)alloc((size_t)4 * HW * 64 * 2);         // 16.6 MB
  int*   seg      = (int*)alloc((size_t)NPTS * 4);
  int*   rankp    = (int*)alloc((size_t)NPTS * 4);
  int*   order    = (int*)alloc((size_t)NPTS * 4);
  int*   bh       = (int*)alloc((size_t)NBLK * NSEG * 4);   // 5.12 MB, [blk][seg]
  int*   basebk   = (int*)alloc((size_t)NBLK * NSEG * 4);   // 5.12 MB, [blk][seg]
  int*   tot      = (int*)alloc(NSEG * 4);
  int*   cnt      = (int*)alloc(NSEG * 4);
  int*   base     = (int*)alloc(NSEG * 4);
  float* part     = (float*)alloc((size_t)720 * 64 * 2 * 4);
  float* ab       = (float*)alloc(64 * 2 * 4);
  float* centroid = (float*)alloc(NSEG * 3 * 4);
  float* lf       = (float*)alloc(NSEG * 64 * 4);
  int*   nonem    = (int*)alloc(NSEG * 4);
  float* gf       = (float*)alloc(NINST * 64 * 4);
  float* tc       = (float*)alloc(NINST * 3 * 4);
  float* ic       = (float*)alloc(NINST * 3 * 4);
  float* zbuf     = (float*)alloc(2048);
  (void)ws_size; (void)n_in; (void)in_sizes; (void)out_size;

  hipMemsetAsync(zbuf, 0, 2048, stream);

  k_hist2<<<NBLK, 256, 0, stream>>>(pts, seg, rankp, bh);
  k_scan2a<<<10, 256, 0, stream>>>(bh, basebk, tot);
  k_scan2b<<<1, 256, 0, stream>>>(tot, base, cnt);
  k_scatter2<<<(NPTS + 255) / 256, 256, 0, stream>>>(seg, rankp, base, basebk, order);
  k_transpose<<<dim3(12, WID, 4), 256, 0, stream>>>(x, xt);
  k_wreorg<<<576, 256, 0, stream>>>(convw, wbuf);
  k_conv_mfma<<<720, 256, 0, stream>>>(xt, wbuf, zbuf, y, part);
  k_bnparams<<<1, 256, 0, stream>>>(part, gamma, beta, ab);
  k_points<<<12500, 256, 0, stream>>>(pts, y, ab, pf);
  k_heads<<<(NPTS + 255) / 256, 256, 0, stream>>>(pf, wseg, bseg, wreg, breg, wemb, bemb,
                                                  o_cls, o_off, o_emb);
  k_seg<<<NSEG, 512, 0, stream>>>(cnt, base, order, pts, pf, wsh, bsh, lf, centroid, nonem);
  k_glob<<<NINST, 64, 0, stream>>>(lf, nonem, centroid, wmos, bmos, gf, tc, ic, o_mos);
  k_tf<<<(NSEG + 255) / 256, 256, 0, stream>>>(lf, gf, centroid, tc, wtf, btf, o_tf);
}

// Round 16
// 326.738 us; speedup vs baseline: 1.0199x; 1.0199x over previous
//
#include <hip/hip_runtime.h>

typedef __attribute__((ext_vector_type(8))) unsigned short u16x8;
typedef __attribute__((ext_vector_type(8))) short s16x8;
typedef __attribute__((ext_vector_type(4))) float f32x4;

#define NPTS 400000
#define HW 32400
#define WID 180
#define NCI 256
#define NCO 64
#define NSEG 2560
#define NINST 256
#define NBLK 500
#define PPB 800    // NBLK * PPB = 400000

__device__ __forceinline__ float bf2f(unsigned short u) {
  union { unsigned int i; float f; } v; v.i = ((unsigned int)u) << 16; return v.f;
}
__device__ __forceinline__ unsigned short f2bf(float f) {
  unsigned int u = __float_as_uint(f);
  return (unsigned short)((u + 0x7fffu + ((u >> 16) & 1u)) >> 16);
}

__device__ __forceinline__ void gld_lds16(const void* g, void* l) {
  __builtin_amdgcn_global_load_lds((const __attribute__((address_space(1))) void*)g,
                                   (__attribute__((address_space(3))) void*)l, 16, 0, 0);
}

// ---------------- K0: NCHW fp32 -> NHWC bf16 transpose (R13 version) ----------------
__global__ __launch_bounds__(256) void k_transpose(const float* __restrict__ x,
                                                   unsigned short* __restrict__ xt) {
  const int bw = blockIdx.x;            // wtile = bw>>2 (0..2), citile = bw&3
  const int h = blockIdx.y, b = blockIdx.z;
  const int w0 = (bw >> 2) * 64, ci0 = (bw & 3) * 64;
  __shared__ float tile[64][68];
  const int t = threadIdx.x;
  const int a = t & 15, c4 = t >> 4;
  const int w4 = a * 4;
  const bool ldok = (w0 + w4) < WID;    // w0=128 tail: 52%4==0, no partial vectors
#pragma unroll
  for (int it = 0; it < 4; ++it) {
    int ci = c4 + it * 16;
    float4 v = make_float4(0.f, 0.f, 0.f, 0.f);
    if (ldok) v = *(const float4*)(x + ((size_t)(b * NCI + ci0 + ci) * WID + h) * WID + w0 + w4);
    tile[w4 + 0][ci] = v.x;
    tile[w4 + 1][ci] = v.y;
    tile[w4 + 2][ci] = v.z;
    tile[w4 + 3][ci] = v.w;
  }
  __syncthreads();
  const int q = t & 7, r = t >> 3;
#pragma unroll
  for (int it = 0; it < 2; ++it) {
    int wl = r + it * 32;
    int w = w0 + wl;
    if (w >= WID) continue;
    const float* row = &tile[wl][q * 8];
    float4 lo = *(const float4*)(row);
    float4 hi = *(const float4*)(row + 4);
    u16x8 o;
    o[0] = f2bf(lo.x); o[1] = f2bf(lo.y); o[2] = f2bf(lo.z); o[3] = f2bf(lo.w);
    o[4] = f2bf(hi.x); o[5] = f2bf(hi.y); o[6] = f2bf(hi.z); o[7] = f2bf(hi.w);
    *(u16x8*)(xt + ((size_t)((b * WID + h) * WID + w)) * NCI + ci0 + q * 8) = o;
  }
}

// ---------------- K0b: conv_w -> wb[tap][chunk][co][32ci] bf16 ----------------
__global__ void k_wreorg(const float* __restrict__ wt, unsigned short* __restrict__ wb) {
  int id = blockIdx.x * 256 + threadIdx.x;
  if (id >= 9 * 8 * 64 * 32) return;
  int cw = id & 31;
  int co = (id >> 5) & 63;
  int chunk = (id >> 11) & 7;
  int tap = id >> 14;
  int ci = chunk * 32 + cw;
  wb[id] = f2bf(wt[((size_t)co * 256 + ci) * 9 + tap]);
}

// ---------------- K1: implicit-GEMM conv, M=192, fused per-block BN partial stats (R13) ----------------
#define ROWB 6272       // 98 * 64
#define RBUF 25600      // 4*ROWB=25088, padded
__global__ __launch_bounds__(256, 3) void k_conv_mfma(const unsigned short* __restrict__ xt,
                                                   const unsigned short* __restrict__ wb,
                                                   const float* __restrict__ zbuf,
                                                   unsigned short* __restrict__ y,
                                                   float* __restrict__ part) {
  const int wg = blockIdx.x;                    // 0..719
  const int lin = (wg & 7) * 90 + (wg >> 3);    // bijective: 720 = 8*90
  const int h2 = lin % 90;
  const int t2 = lin / 90;                      // b*2 + wth
  const int wth = t2 & 1, b = t2 >> 1;
  const int h0 = h2 * 2;
  const int w0 = wth * 96;
  __shared__ unsigned char strip[2][RBUF];
  __shared__ float redS[2][2][2][16], redQ[2][2][2][16]; // [mh][nh][nf][l15]
  const int tid = threadIdx.x;
  const int lane = tid & 63, wv = tid >> 6;
  const int mh = wv >> 1, nh = wv & 1;
  const int l15 = lane & 15, lk = lane >> 4;

  const char* srcs[7];
#pragma unroll
  for (int k = 0; k < 7; ++k) {
    int j = wv + k * 4;
    int g = j * 64 + lane;          // 16B-unit index
    int pxlin = g >> 2, sub = g & 3;
    int row = pxlin / 98;
    int px = pxlin - row * 98;
    int hh = h0 + row - 1;
    int worig = w0 + px - 1;
    bool valid = (j < 25) && (pxlin < 392) &&
                 (hh >= 0) && (hh < WID) && (worig >= 0) && (worig < WID);
    int cig = sub ^ ((px >> 1) & 3);
    srcs[k] = valid
        ? (const char*)(xt + ((size_t)((b * WID + hh) * WID + worig)) * NCI + cig * 8)
        : (const char*)zbuf + lane * 16;   // +chunk*64 stays inside 2KB
  }

  f32x4 acc[6][2];
#pragma unroll
  for (int i = 0; i < 6; ++i)
#pragma unroll
    for (int j = 0; j < 2; ++j) { acc[i][j][0] = 0.f; acc[i][j][1] = 0.f; acc[i][j][2] = 0.f; acc[i][j][3] = 0.f; }

  auto stage = [&](unsigned char* buf, int chunk) {
#pragma unroll
    for (int k = 0; k < 7; ++k) {
      int j = wv + k * 4;
      if (j >= 25) break;            // wave-uniform
      gld_lds16(srcs[k] + chunk * 64, buf + j * 1024);
    }
  };

  stage(strip[0], 0);
  asm volatile("s_waitcnt vmcnt(0)" ::: "memory");
  __syncthreads();

  const unsigned short* wco[2];
#pragma unroll
  for (int nf = 0; nf < 2; ++nf)
    wco[nf] = wb + (size_t)((nh * 2 + nf) * 16 + l15) * 32 + lk * 8;

  for (int chunk = 0; chunk < 8; ++chunk) {
    s16x8 bfr[9][2];
#pragma unroll
    for (int tap = 0; tap < 9; ++tap)
#pragma unroll
      for (int nf = 0; nf < 2; ++nf)
        bfr[tap][nf] = *(const s16x8*)(wco[nf] + (size_t)(tap * 8 + chunk) * 2048);
    if (chunk < 7) stage(strip[(chunk + 1) & 1], chunk + 1);
    const unsigned char* buf = strip[chunk & 1];
#pragma unroll
    for (int tap = 0; tap < 9; ++tap) {
      const int dh = tap / 3, dw = tap % 3;
      s16x8 afr[6];
#pragma unroll
      for (int i = 0; i < 6; ++i) {
        int wp = i * 16 + l15 + dw;
        int byte = (mh + dh) * ROWB + wp * 64 + ((lk ^ ((wp >> 1) & 3)) * 16);
        afr[i] = *(const s16x8*)(buf + byte);
      }
#pragma unroll
      for (int i = 0; i < 6; ++i)
#pragma unroll
        for (int nf = 0; nf < 2; ++nf)
          acc[i][nf] = __builtin_amdgcn_mfma_f32_16x16x32_bf16(afr[i], bfr[tap][nf], acc[i][nf], 0, 0, 0);
    }
    asm volatile("s_waitcnt vmcnt(0)" ::: "memory");
    __syncthreads();
  }

  // epilogue: y store + per-channel partial BN stats (valid pixels only)
  const int r4 = lk * 4;
  const int hrow = h0 + mh;
  float s[2] = {0.f, 0.f}, q[2] = {0.f, 0.f};
#pragma unroll
  for (int i = 0; i < 6; ++i) {
#pragma unroll
    for (int nf = 0; nf < 2; ++nf) {
      int co = (nh * 2 + nf) * 16 + l15;
#pragma unroll
      for (int j = 0; j < 4; ++j) {
        int w = w0 + i * 16 + r4 + j;
        if (w < WID) {
          float v = acc[i][nf][j];
          y[((size_t)(b * HW) + hrow * WID + w) * 64 + co] = f2bf(v);
          s[nf] += v; q[nf] = fmaf(v, v, q[nf]);
        }
      }
    }
  }
#pragma unroll
  for (int nf = 0; nf < 2; ++nf) {
    s[nf] += __shfl_xor(s[nf], 16); s[nf] += __shfl_xor(s[nf], 32);
    q[nf] += __shfl_xor(q[nf], 16); q[nf] += __shfl_xor(q[nf], 32);
  }
  if (lk == 0) {
#pragma unroll
    for (int nf = 0; nf < 2; ++nf) { redS[mh][nh][nf][l15] = s[nf]; redQ[mh][nh][nf][l15] = q[nf]; }
  }
  __syncthreads();
  if (tid < 64) {
    int co = tid;
    int nhh = co >> 5, nff = (co >> 4) & 1, ll = co & 15;
    part[((size_t)wg * 64 + co) * 2 + 0] = redS[0][nhh][nff][ll] + redS[1][nhh][nff][ll];
    part[((size_t)wg * 64 + co) * 2 + 1] = redQ[0][nhh][nff][ll] + redQ[1][nhh][nff][ll];
  }
}

// ---------------- K2b: final BN scale/shift from 720 partials (4-way parallel) ----------------
__global__ void k_bnparams(const float* __restrict__ part, const float* __restrict__ gamma,
                           const float* __restrict__ beta, float* __restrict__ ab) {
  __shared__ float ls[256], lss[256];
  const int t = threadIdx.x;            // 256
  const int c = t & 63, g = t >> 6;     // 4 groups per channel
  float s = 0.f, ss = 0.f;
  for (int k = g; k < 720; k += 4) {
    s += part[((size_t)k * 64 + c) * 2];
    ss += part[((size_t)k * 64 + c) * 2 + 1];
  }
  ls[t] = s; lss[t] = ss;
  __syncthreads();
  if (t < 64) {
    s = ls[t] + ls[t + 64] + ls[t + 128] + ls[t + 192];
    ss = lss[t] + lss[t + 64] + lss[t + 128] + lss[t + 192];
    float mu = s / 129600.f;
    float var = ss / 129600.f - mu * mu;
    float a = rsqrtf(var + 1e-5f) * gamma[t];
    ab[t * 2] = a; ab[t * 2 + 1] = beta[t] - mu * a;
  }
}

// ---------------- K4: bilinear gather with fused BN+ReLU, 8 points/wave ----------------
__global__ __launch_bounds__(256) void k_points(const float* __restrict__ pts,
                         const unsigned short* __restrict__ y,
                         const float* __restrict__ ab,
                         unsigned short* __restrict__ pf) {
  const int gid = blockIdx.x * 256 + threadIdx.x;
  const int lane = gid & 63;
  const int wid = gid >> 6;
  const float sa = ab[lane * 2], sb = ab[lane * 2 + 1];
#pragma unroll
  for (int it = 0; it < 8; ++it) {
    int p = wid * 8 + it;  // 12500 blocks * 4 waves * 8 = 400000
    const float* pr = pts + (size_t)p * 9;
    float pbf = pr[0], xx = pr[1], yy = pr[2];
    int b = (int)pbf;
    float px = (xx - (-54.0f)) / 0.6f;
    float py = (yy - (-54.0f)) / 0.6f;
    int x0 = (int)floorf(px); x0 = min(max(x0, 0), WID - 1);
    int x1 = min(x0 + 1, WID - 1);
    int y0 = (int)floorf(py); y0 = min(max(y0, 0), WID - 1);
    int y1 = min(y0 + 1, WID - 1);
    float x0f = (float)x0, x1f = (float)x1, y0f = (float)y0, y1f = (float)y1;
    float wa = (x1f - px) * (y1f - py);
    float wb = (x1f - px) * (py - y0f);
    float wc = (px - x0f) * (y1f - py);
    float wd = (px - x0f) * (py - y0f);
    int i00 = y0 * WID + x0;
    int dx = x1 - x0;
    int dy = (y1 - y0) * WID;
    const unsigned short* bb = y + ((size_t)b * HW) * 64 + lane;
    float Ia = fmaf(bf2f(bb[(size_t)i00 * 64]), sa, sb);             Ia = Ia > 0.f ? Ia : 0.f;
    float Ic = fmaf(bf2f(bb[(size_t)(i00 + dx) * 64]), sa, sb);      Ic = Ic > 0.f ? Ic : 0.f;
    float Ib = fmaf(bf2f(bb[(size_t)(i00 + dy) * 64]), sa, sb);      Ib = Ib > 0.f ? Ib : 0.f;
    float Id = fmaf(bf2f(bb[(size_t)(i00 + dy + dx) * 64]), sa, sb); Id = Id > 0.f ? Id : 0.f;
    float f = wa * Ia + wb * Ib + wc * Ic + wd * Id;
    pf[(size_t)p * 64 + lane] = f2bf(f);
  }
}

// ---------------- K4b: point heads (cls/offset/embedding), vectorized pf reads ----------------
__global__ void k_heads(const unsigned short* __restrict__ pf,
                        const float* __restrict__ wseg, const float* __restrict__ bseg,
                        const float* __restrict__ wreg, const float* __restrict__ breg,
                        const float* __restrict__ wemb, const float* __restrict__ bemb,
                        float* __restrict__ ocls, float* __restrict__ ooff, float* __restrict__ oemb) {
  const int p = blockIdx.x * 256 + threadIdx.x;
  if (p >= NPTS) return;
  float a0 = bseg[0], a1 = bseg[1], a2 = bseg[2];
  float r0 = breg[0], r1 = breg[1], r2 = breg[2];
  float e0 = bemb[0], e1 = bemb[1];
  const u16x8* q = (const u16x8*)(pf + (size_t)p * 64);
#pragma unroll
  for (int g = 0; g < 8; ++g) {
    u16x8 v8 = q[g];
#pragma unroll
    for (int k = 0; k < 8; ++k) {
      int kk = g * 8 + k;
      float v = bf2f(v8[k]);
      a0 = fmaf(v, wseg[kk * 3 + 0], a0);
      a1 = fmaf(v, wseg[kk * 3 + 1], a1);
      a2 = fmaf(v, wseg[kk * 3 + 2], a2);
      r0 = fmaf(v, wreg[kk * 3 + 0], r0);
      r1 = fmaf(v, wreg[kk * 3 + 1], r1);
      r2 = fmaf(v, wreg[kk * 3 + 2], r2);
      e0 = fmaf(v, wemb[kk * 2 + 0], e0);
      e1 = fmaf(v, wemb[kk * 2 + 1], e1);
    }
  }
  ocls[p * 3 + 0] = a0; ocls[p * 3 + 1] = a1; ocls[p * 3 + 2] = a2;
  ooff[p * 3 + 0] = r0; ooff[p * 3 + 1] = r1; ooff[p * 3 + 2] = r2;
  oemb[p * 2 + 0] = e0; oemb[p * 2 + 1] = e1;
}

// ---------------- K5: LDS-privatized histogram + local rank (coalesced [blk][seg] writeback) ----------------
__global__ __launch_bounds__(256) void k_hist2(const float* __restrict__ pts,
                                               int* __restrict__ seg, int* __restrict__ rankp,
                                               int* __restrict__ bh) {
  __shared__ int lc[NSEG];
  const int t = threadIdx.x, blk = blockIdx.x;
  for (int i = t; i < NSEG; i += 256) lc[i] = 0;
  __syncthreads();
  const int p0 = blk * PPB;
  for (int i = t; i < PPB; i += 256) {
    int p = p0 + i;
    const float* pr = pts + (size_t)p * 9;
    int b = (int)pr[0];
    int sw = (int)pr[6];
    int ins = (int)pr[7];
    int s = (b * 64 + ins) * 10 + sw;
    seg[p] = s;
    rankp[p] = atomicAdd(&lc[s], 1);
  }
  __syncthreads();
  for (int i = t; i < NSEG; i += 256) bh[(size_t)blk * NSEG + i] = lc[i];
}

// ---------------- K6a: per-segment prefix across blocks (coalesced row sweeps) ----------------
__global__ void k_scan2a(const int* __restrict__ bh, int* __restrict__ basebk,
                         int* __restrict__ tot) {
  const int s = blockIdx.x * 256 + threadIdx.x;  // 0..2559
  int acc = 0;
  for (int b = 0; b < NBLK; ++b) {
    int v = bh[(size_t)b * NSEG + s];
    basebk[(size_t)b * NSEG + s] = acc;
    acc += v;
  }
  tot[s] = acc;
}

// ---------------- K6b: exclusive scan of segment totals ----------------
__global__ void k_scan2b(const int* __restrict__ tot, int* __restrict__ base,
                         int* __restrict__ cnt) {
  __shared__ int csum[256];
  const int t = threadIdx.x;
  int loc[10]; int run = 0;
#pragma unroll
  for (int k = 0; k < 10; ++k) { loc[k] = tot[t * 10 + k]; run += loc[k]; }
  csum[t] = run;
  __syncthreads();
  if (t == 0) {
    int a = 0;
    for (int i = 0; i < 256; ++i) { int v = csum[i]; csum[i] = a; a += v; }
  }
  __syncthreads();
  int acc = csum[t];
#pragma unroll
  for (int k = 0; k < 10; ++k) {
    int s = t * 10 + k;
    base[s] = acc; cnt[s] = loc[k];
    acc += loc[k];
  }
}

// ---------------- K7: atomic-free scatter ----------------
__global__ void k_scatter2(const int* __restrict__ seg, const int* __restrict__ rankp,
                           const int* __restrict__ base, const int* __restrict__ basebk,
                           int* __restrict__ order) {
  const int p = blockIdx.x * 256 + threadIdx.x;
  if (p < NPTS) {
    int s = seg[p];
    int blk = p / PPB;
    order[base[s] + basebk[(size_t)blk * NSEG + s] + rankp[p]] = p;
  }
}

// ---------------- K8: per-segment centroid + shape max + feat max (8 waves) ----------------
__global__ __launch_bounds__(512) void k_seg(const int* __restrict__ cnt, const int* __restrict__ base,
                      const int* __restrict__ order, const float* __restrict__ pts,
                      const unsigned short* __restrict__ pf,
                      const float* __restrict__ wsh, const float* __restrict__ bsh,
                      float* __restrict__ lf, float* __restrict__ centroid,
                      int* __restrict__ nonempty) {
  const int s = blockIdx.x;
  const int t = threadIdx.x, lane = t & 63, wv = t >> 6;
  const int n = cnt[s], bs = base[s];
  float sx = 0.f, sy = 0.f, sz = 0.f;
  for (int i = t; i < n; i += 512) {
    int p = order[bs + i];
    const float* pr = pts + (size_t)p * 9;
    sx += pr[1]; sy += pr[2]; sz += pr[3];
  }
#pragma unroll
  for (int m = 32; m > 0; m >>= 1) {
    sx += __shfl_xor(sx, m); sy += __shfl_xor(sy, m); sz += __shfl_xor(sz, m);
  }
  __shared__ float red[3][8];
  __shared__ float csh[3];
  if (lane == 0) { red[0][wv] = sx; red[1][wv] = sy; red[2][wv] = sz; }
  __syncthreads();
  if (t == 0) {
    float dn = (float)max(n, 1);
    float ax = 0.f, ay = 0.f, az = 0.f;
#pragma unroll
    for (int k = 0; k < 8; ++k) { ax += red[0][k]; ay += red[1][k]; az += red[2][k]; }
    csh[0] = ax / dn; csh[1] = ay / dn; csh[2] = az / dn;
  }
  __syncthreads();
  const float cx = csh[0], cy = csh[1], cz = csh[2];
  const float w0 = wsh[lane], w1 = wsh[64 + lane], w2 = wsh[128 + lane], bb = bsh[lane];
  float smax = -INFINITY, lmax = -INFINITY;
  for (int i = wv; i < n; i += 8) {
    int p = order[bs + i];
    const float* pr = pts + (size_t)p * 9;
    float sv = fmaf(pr[1] - cx, w0, fmaf(pr[2] - cy, w1, fmaf(pr[3] - cz, w2, bb)));
    smax = fmaxf(smax, sv);
    lmax = fmaxf(lmax, bf2f(pf[(size_t)p * 64 + lane]));
  }
  __shared__ float rs[8][64], rl[8][64];
  rs[wv][lane] = smax; rl[wv][lane] = lmax;
  __syncthreads();
  if (wv == 0) {
#pragma unroll
    for (int k = 1; k < 8; ++k) {
      smax = fmaxf(smax, rs[k][lane]);
      lmax = fmaxf(lmax, rl[k][lane]);
    }
    bool ne = n > 0;
    lf[s * 64 + lane] = (ne ? lmax : 0.f) + (ne ? smax : 0.f);
    if (lane == 0) {
      nonempty[s] = ne ? 1 : 0;
      centroid[s * 3 + 0] = cx; centroid[s * 3 + 1] = cy; centroid[s * 3 + 2] = cz;
    }
  }
}

// ---------------- K9: per-instance globals + sweep min/max + inst_mos ----------------
__global__ void k_glob(const float* __restrict__ lf, const int* __restrict__ ne,
                       const float* __restrict__ centroid,
                       const float* __restrict__ wmos, const float* __restrict__ bmos,
                       float* __restrict__ gf, float* __restrict__ tc, float* __restrict__ ic,
                       float* __restrict__ omos) {
  const int i = blockIdx.x;
  const int t = threadIdx.x; // 64 threads
  float g = -INFINITY;
  int maxsw = -1, minsw = 10;
  bool any = false;
#pragma unroll
  for (int s = 0; s < 10; ++s) {
    int idx = i * 10 + s;
    bool e = ne[idx] != 0;
    float v = lf[idx * 64 + t];
    g = fmaxf(g, e ? v : -INFINITY);
    if (e) { any = true; maxsw = s; minsw = min(minsw, s); }
  }
  float gv = any ? g : 0.f;
  gf[i * 64 + t] = gv;
  int idxmax = min(max(i * 10 + maxsw, 0), NSEG - 1);
  int idxmin = min(max(i * 10 + minsw, 0), NSEG - 1);
  float tcx = centroid[idxmax * 3 + 0], tcy = centroid[idxmax * 3 + 1], tcz = centroid[idxmax * 3 + 2];
  float icx = centroid[idxmin * 3 + 0], icy = centroid[idxmin * 3 + 1], icz = centroid[idxmin * 3 + 2];
  if (t == 0) {
    tc[i * 3 + 0] = tcx; tc[i * 3 + 1] = tcy; tc[i * 3 + 2] = tcz;
    ic[i * 3 + 0] = icx; ic[i * 3 + 1] = icy; ic[i * 3 + 2] = icz;
  }
  float r = gv * wmos[t];
#pragma unroll
  for (int m = 32; m > 0; m >>= 1) r += __shfl_xor(r, m);
  if (t == 0) {
    r += icx * wmos[64] + icy * wmos[65] + icz * wmos[66];
    r += tcx * wmos[67] + tcy * wmos[68] + tcz * wmos[69];
    omos[i] = r + bmos[0];
  }
}

// ---------------- K10: locals_tf = locals_cat(134) @ w_tf(134x7) ----------------
__global__ void k_tf(const float* __restrict__ lf, const float* __restrict__ gf,
                     const float* __restrict__ centroid, const float* __restrict__ tc,
                     const float* __restrict__ wtf, const float* __restrict__ btf,
                     float* __restrict__ otf) {
  const int r = blockIdx.x * 256 + threadIdx.x;
  if (r >= NSEG) return;
  const int i = r / 10;
  float acc[7];
#pragma unroll
  for (int j = 0; j < 7; ++j) acc[j] = btf[j];
  for (int k = 0; k < 64; ++k) {
    float v = lf[r * 64 + k];
#pragma unroll
    for (int j = 0; j < 7; ++j) acc[j] = fmaf(v, wtf[k * 7 + j], acc[j]);
  }
  for (int k = 0; k < 64; ++k) {
    float v = gf[i * 64 + k];
#pragma unroll
    for (int j = 0; j < 7; ++j) acc[j] = fmaf(v, wtf[(64 + k) * 7 + j], acc[j]);
  }
#pragma unroll
  for (int c = 0; c < 3; ++c) {
    float v = centroid[r * 3 + c];
#pragma unroll
    for (int j = 0; j < 7; ++j) acc[j] = fmaf(v, wtf[(128 + c) * 7 + j], acc[j]);
  }
#pragma unroll
  for (int c = 0; c < 3; ++c) {
    float v = tc[i * 3 + c];
#pragma unroll
    for (int j = 0; j < 7; ++j) acc[j] = fmaf(v, wtf[(131 + c) * 7 + j], acc[j]);
  }
#pragma unroll
  for (int j = 0; j < 7; ++j) otf[r * 7 + j] = acc[j];
}

extern "C" void kernel_launch(void* const* d_in, const int* in_sizes, int n_in,
                              void* d_out, int out_size, void* d_ws, size_t ws_size,
                              hipStream_t stream) {
  const float* pts   = (const float*)d_in[0];
  const float* x     = (const float*)d_in[1];
  const float* convw = (const float*)d_in[2];
  const float* gamma = (const float*)d_in[3];
  const float* beta  = (const float*)d_in[4];
  const float* wseg  = (const float*)d_in[5];
  const float* bseg  = (const float*)d_in[6];
  const float* wreg  = (const float*)d_in[7];
  const float* breg  = (const float*)d_in[8];
  const float* wemb  = (const float*)d_in[9];
  const float* bemb  = (const float*)d_in[10];
  const float* wsh   = (const float*)d_in[11];
  const float* bsh   = (const float*)d_in[12];
  const float* wtf   = (const float*)d_in[13];
  const float* btf   = (const float*)d_in[14];
  const float* wmos  = (const float*)d_in[15];
  const float* bmos  = (const float*)d_in[16];

  float* out = (float*)d_out;
  float* o_cls = out;                 // 400000 x 3
  float* o_off = out + 1200000;       // 400000 x 3
  float* o_emb = out + 2400000;       // 400000 x 2
  float* o_tf  = out + 3200000;       // 2560 x 7
  float* o_mos = out + 3217920;       // 256 x 1

  char* wsp = (char*)d_ws;
  size_t off = 0;
  auto alloc = [&](size_t bytes) -> void* {
    void* p = wsp + off;
    off = (off + bytes + 255) & ~(size_t)255;
    return p;
  };
  // xt dead after conv -> pf aliases it.
  unsigned short* xt   = (unsigned short*)alloc((size_t)4 * WID * WID * NCI * 2); // 66.4 MB
  unsigned short* pf   = xt;
  unsigned short* wbuf = (unsigned short*)alloc((size_t)9 * 8 * 64 * 32 * 2);
  unsigned short* y    = (unsigned short*)alloc((size_t)4 * HW * 64 * 2);         // 16.6 MB
  int*   seg      = (int*)alloc((size_t)NPTS * 4);
  int*   rankp    = (int*)alloc((size_t)NPTS * 4);
  int*   order    = (int*)alloc((size_t)NPTS * 4);
  int*   bh       = (int*)alloc((size_t)NBLK * NSEG * 4);   // 5.12 MB, [blk][seg]
  int*   basebk   = (int*)alloc((size_t)NBLK * NSEG * 4);   // 5.12 MB, [blk][seg]
  int*   tot      = (int*)alloc(NSEG * 4);
  int*   cnt      = (int*)alloc(NSEG * 4);
  int*   base     = (int*)alloc(NSEG * 4);
  float* part     = (float*)alloc((size_t)720 * 64 * 2 * 4);
  float* ab       = (float*)alloc(64 * 2 * 4);
  float* centroid = (float*)alloc(NSEG * 3 * 4);
  float* lf       = (float*)alloc(NSEG * 64 * 4);
  int*   nonem    = (int*)alloc(NSEG * 4);
  float* gf       = (float*)alloc(NINST * 64 * 4);
  float* tc       = (float*)alloc(NINST * 3 * 4);
  float* ic       = (float*)alloc(NINST * 3 * 4);
  float* zbuf     = (float*)alloc(2048);
  (void)ws_size; (void)n_in; (void)in_sizes; (void)out_size;

  hipMemsetAsync(zbuf, 0, 2048, stream);

  k_hist2<<<NBLK, 256, 0, stream>>>(pts, seg, rankp, bh);
  k_scan2a<<<10, 256, 0, stream>>>(bh, basebk, tot);
  k_scan2b<<<1, 256, 0, stream>>>(tot, base, cnt);
  k_scatter2<<<(NPTS + 255) / 256, 256, 0, stream>>>(seg, rankp, base, basebk, order);
  k_transpose<<<dim3(12, WID, 4), 256, 0, stream>>>(x, xt);
  k_wreorg<<<576, 256, 0, stream>>>(convw, wbuf);
  k_conv_mfma<<<720, 256, 0, stream>>>(xt, wbuf, zbuf, y, part);
  k_bnparams<<<1, 256, 0, stream>>>(part, gamma, beta, ab);
  k_points<<<12500, 256, 0, stream>>>(pts, y, ab, pf);
  k_heads<<<(NPTS + 255) / 256, 256, 0, stream>>>(pf, wseg, bseg, wreg, breg, wemb, bemb,
                                                  o_cls, o_off, o_emb);
  k_seg<<<NSEG, 512, 0, stream>>>(cnt, base, order, pts, pf, wsh, bsh, lf, centroid, nonem);
  k_glob<<<NINST, 64, 0, stream>>>(lf, nonem, centroid, wmos, bmos, gf, tc, ic, o_mos);
  k_tf<<<(NSEG + 255) / 256, 256, 0, stream>>>(lf, gf, centroid, tc, wtf, btf, o_tf);
}

// Round 17
// 299.424 us; speedup vs baseline: 1.1129x; 1.0912x over previous
//
#include <hip/hip_runtime.h>

typedef __attribute__((ext_vector_type(8))) unsigned short u16x8;
typedef __attribute__((ext_vector_type(8))) short s16x8;
typedef __attribute__((ext_vector_type(4))) float f32x4;

#define NPTS 400000
#define HW 32400
#define WID 180
#define NCI 256
#define NCO 64
#define NSEG 2560
#define NINST 256
#define NBLK 500
#define PPB 800    // NBLK * PPB = 400000

__device__ __forceinline__ float bf2f(unsigned short u) {
  union { unsigned int i; float f; } v; v.i = ((unsigned int)u) << 16; return v.f;
}
__device__ __forceinline__ unsigned short f2bf(float f) {
  unsigned int u = __float_as_uint(f);
  return (unsigned short)((u + 0x7fffu + ((u >> 16) & 1u)) >> 16);
}

__device__ __forceinline__ void gld_lds16(const void* g, void* l) {
  __builtin_amdgcn_global_load_lds((const __attribute__((address_space(1))) void*)g,
                                   (__attribute__((address_space(3))) void*)l, 16, 0, 0);
}

// ---------------- K0: NCHW fp32 -> NHWC bf16 transpose ----------------
__global__ __launch_bounds__(256) void k_transpose(const float* __restrict__ x,
                                                   unsigned short* __restrict__ xt) {
  const int bw = blockIdx.x;            // wtile = bw>>2 (0..2), citile = bw&3
  const int h = blockIdx.y, b = blockIdx.z;
  const int w0 = (bw >> 2) * 64, ci0 = (bw & 3) * 64;
  __shared__ float tile[64][68];
  const int t = threadIdx.x;
  const int a = t & 15, c4 = t >> 4;
  const int w4 = a * 4;
  const bool ldok = (w0 + w4) < WID;    // w0=128 tail: 52%4==0, no partial vectors
#pragma unroll
  for (int it = 0; it < 4; ++it) {
    int ci = c4 + it * 16;
    float4 v = make_float4(0.f, 0.f, 0.f, 0.f);
    if (ldok) v = *(const float4*)(x + ((size_t)(b * NCI + ci0 + ci) * WID + h) * WID + w0 + w4);
    tile[w4 + 0][ci] = v.x;
    tile[w4 + 1][ci] = v.y;
    tile[w4 + 2][ci] = v.z;
    tile[w4 + 3][ci] = v.w;
  }
  __syncthreads();
  const int q = t & 7, r = t >> 3;
#pragma unroll
  for (int it = 0; it < 2; ++it) {
    int wl = r + it * 32;
    int w = w0 + wl;
    if (w >= WID) continue;
    const float* row = &tile[wl][q * 8];
    float4 lo = *(const float4*)(row);
    float4 hi = *(const float4*)(row + 4);
    u16x8 o;
    o[0] = f2bf(lo.x); o[1] = f2bf(lo.y); o[2] = f2bf(lo.z); o[3] = f2bf(lo.w);
    o[4] = f2bf(hi.x); o[5] = f2bf(hi.y); o[6] = f2bf(hi.z); o[7] = f2bf(hi.w);
    *(u16x8*)(xt + ((size_t)((b * WID + h) * WID + w)) * NCI + ci0 + q * 8) = o;
  }
}

// ---------------- K0b: conv_w -> wb[tap][chunk][co][32ci] bf16 ----------------
__global__ void k_wreorg(const float* __restrict__ wt, unsigned short* __restrict__ wb) {
  int id = blockIdx.x * 256 + threadIdx.x;
  if (id >= 9 * 8 * 64 * 32) return;
  int cw = id & 31;
  int co = (id >> 5) & 63;
  int chunk = (id >> 11) & 7;
  int tap = id >> 14;
  int ci = chunk * 32 + cw;
  wb[id] = f2bf(wt[((size_t)co * 256 + ci) * 9 + tap]);
}

// ---------------- K1: implicit-GEMM conv, M=192, fused per-block BN partial stats ----------------
#define ROWB 6272       // 98 * 64
#define RBUF 25600      // 4*ROWB=25088, padded
__global__ __launch_bounds__(256, 3) void k_conv_mfma(const unsigned short* __restrict__ xt,
                                                   const unsigned short* __restrict__ wb,
                                                   const float* __restrict__ zbuf,
                                                   unsigned short* __restrict__ y,
                                                   float* __restrict__ part) {
  const int wg = blockIdx.x;                    // 0..719
  const int lin = (wg & 7) * 90 + (wg >> 3);    // bijective: 720 = 8*90
  const int h2 = lin % 90;
  const int t2 = lin / 90;                      // b*2 + wth
  const int wth = t2 & 1, b = t2 >> 1;
  const int h0 = h2 * 2;
  const int w0 = wth * 96;
  __shared__ unsigned char strip[2][RBUF];
  __shared__ float redS[2][2][2][16], redQ[2][2][2][16]; // [mh][nh][nf][l15]
  const int tid = threadIdx.x;
  const int lane = tid & 63, wv = tid >> 6;
  const int mh = wv >> 1, nh = wv & 1;
  const int l15 = lane & 15, lk = lane >> 4;

  const char* srcs[7];
#pragma unroll
  for (int k = 0; k < 7; ++k) {
    int j = wv + k * 4;
    int g = j * 64 + lane;          // 16B-unit index
    int pxlin = g >> 2, sub = g & 3;
    int row = pxlin / 98;
    int px = pxlin - row * 98;
    int hh = h0 + row - 1;
    int worig = w0 + px - 1;
    bool valid = (j < 25) && (pxlin < 392) &&
                 (hh >= 0) && (hh < WID) && (worig >= 0) && (worig < WID);
    int cig = sub ^ ((px >> 1) & 3);
    srcs[k] = valid
        ? (const char*)(xt + ((size_t)((b * WID + hh) * WID + worig)) * NCI + cig * 8)
        : (const char*)zbuf + lane * 16;   // +chunk*64 stays inside 2KB
  }

  f32x4 acc[6][2];
#pragma unroll
  for (int i = 0; i < 6; ++i)
#pragma unroll
    for (int j = 0; j < 2; ++j) { acc[i][j][0] = 0.f; acc[i][j][1] = 0.f; acc[i][j][2] = 0.f; acc[i][j][3] = 0.f; }

  auto stage = [&](unsigned char* buf, int chunk) {
#pragma unroll
    for (int k = 0; k < 7; ++k) {
      int j = wv + k * 4;
      if (j >= 25) break;            // wave-uniform
      gld_lds16(srcs[k] + chunk * 64, buf + j * 1024);
    }
  };

  stage(strip[0], 0);
  asm volatile("s_waitcnt vmcnt(0)" ::: "memory");
  __syncthreads();

  const unsigned short* wco[2];
#pragma unroll
  for (int nf = 0; nf < 2; ++nf)
    wco[nf] = wb + (size_t)((nh * 2 + nf) * 16 + l15) * 32 + lk * 8;

  for (int chunk = 0; chunk < 8; ++chunk) {
    s16x8 bfr[9][2];
#pragma unroll
    for (int tap = 0; tap < 9; ++tap)
#pragma unroll
      for (int nf = 0; nf < 2; ++nf)
        bfr[tap][nf] = *(const s16x8*)(wco[nf] + (size_t)(tap * 8 + chunk) * 2048);
    if (chunk < 7) stage(strip[(chunk + 1) & 1], chunk + 1);
    const unsigned char* buf = strip[chunk & 1];
#pragma unroll
    for (int tap = 0; tap < 9; ++tap) {
      const int dh = tap / 3, dw = tap % 3;
      s16x8 afr[6];
#pragma unroll
      for (int i = 0; i < 6; ++i) {
        int wp = i * 16 + l15 + dw;
        int byte = (mh + dh) * ROWB + wp * 64 + ((lk ^ ((wp >> 1) & 3)) * 16);
        afr[i] = *(const s16x8*)(buf + byte);
      }
#pragma unroll
      for (int i = 0; i < 6; ++i)
#pragma unroll
        for (int nf = 0; nf < 2; ++nf)
          acc[i][nf] = __builtin_amdgcn_mfma_f32_16x16x32_bf16(afr[i], bfr[tap][nf], acc[i][nf], 0, 0, 0);
    }
    asm volatile("s_waitcnt vmcnt(0)" ::: "memory");
    __syncthreads();
  }

  // epilogue: y store + per-channel partial BN stats (valid pixels only)
  const int r4 = lk * 4;
  const int hrow = h0 + mh;
  float s[2] = {0.f, 0.f}, q[2] = {0.f, 0.f};
#pragma unroll
  for (int i = 0; i < 6; ++i) {
#pragma unroll
    for (int nf = 0; nf < 2; ++nf) {
      int co = (nh * 2 + nf) * 16 + l15;
#pragma unroll
      for (int j = 0; j < 4; ++j) {
        int w = w0 + i * 16 + r4 + j;
        if (w < WID) {
          float v = acc[i][nf][j];
          y[((size_t)(b * HW) + hrow * WID + w) * 64 + co] = f2bf(v);
          s[nf] += v; q[nf] = fmaf(v, v, q[nf]);
        }
      }
    }
  }
#pragma unroll
  for (int nf = 0; nf < 2; ++nf) {
    s[nf] += __shfl_xor(s[nf], 16); s[nf] += __shfl_xor(s[nf], 32);
    q[nf] += __shfl_xor(q[nf], 16); q[nf] += __shfl_xor(q[nf], 32);
  }
  if (lk == 0) {
#pragma unroll
    for (int nf = 0; nf < 2; ++nf) { redS[mh][nh][nf][l15] = s[nf]; redQ[mh][nh][nf][l15] = q[nf]; }
  }
  __syncthreads();
  if (tid < 64) {
    int co = tid;
    int nhh = co >> 5, nff = (co >> 4) & 1, ll = co & 15;
    part[((size_t)wg * 64 + co) * 2 + 0] = redS[0][nhh][nff][ll] + redS[1][nhh][nff][ll];
    part[((size_t)wg * 64 + co) * 2 + 1] = redQ[0][nhh][nff][ll] + redQ[1][nhh][nff][ll];
  }
}

// ---------------- K2b: final BN scale/shift from 720 partials ----------------
__global__ void k_bnparams(const float* __restrict__ part, const float* __restrict__ gamma,
                           const float* __restrict__ beta, float* __restrict__ ab) {
  const int t = threadIdx.x; // 64
  float s = 0.f, ss = 0.f;
  for (int k = 0; k < 720; ++k) { s += part[((size_t)k * 64 + t) * 2]; ss += part[((size_t)k * 64 + t) * 2 + 1]; }
  float mu = s / 129600.f;
  float var = ss / 129600.f - mu * mu;
  float a = rsqrtf(var + 1e-5f) * gamma[t];
  ab[t * 2] = a; ab[t * 2 + 1] = beta[t] - mu * a;
}

// ---------------- K4: bilinear gather with fused BN+ReLU, 8 points/wave ----------------
__global__ __launch_bounds__(256) void k_points(const float* __restrict__ pts,
                         const unsigned short* __restrict__ y,
                         const float* __restrict__ ab,
                         unsigned short* __restrict__ pf) {
  const int gid = blockIdx.x * 256 + threadIdx.x;
  const int lane = gid & 63;
  const int wid = gid >> 6;
  const float sa = ab[lane * 2], sb = ab[lane * 2 + 1];
#pragma unroll
  for (int it = 0; it < 8; ++it) {
    int p = wid * 8 + it;  // 12500 blocks * 4 waves * 8 = 400000
    const float* pr = pts + (size_t)p * 9;
    float pbf = pr[0], xx = pr[1], yy = pr[2];
    int b = (int)pbf;
    float px = (xx - (-54.0f)) / 0.6f;
    float py = (yy - (-54.0f)) / 0.6f;
    int x0 = (int)floorf(px); x0 = min(max(x0, 0), WID - 1);
    int x1 = min(x0 + 1, WID - 1);
    int y0 = (int)floorf(py); y0 = min(max(y0, 0), WID - 1);
    int y1 = min(y0 + 1, WID - 1);
    float x0f = (float)x0, x1f = (float)x1, y0f = (float)y0, y1f = (float)y1;
    float wa = (x1f - px) * (y1f - py);
    float wb = (x1f - px) * (py - y0f);
    float wc = (px - x0f) * (y1f - py);
    float wd = (px - x0f) * (py - y0f);
    int i00 = y0 * WID + x0;
    int dx = x1 - x0;
    int dy = (y1 - y0) * WID;
    const unsigned short* bb = y + ((size_t)b * HW) * 64 + lane;
    float Ia = fmaf(bf2f(bb[(size_t)i00 * 64]), sa, sb);             Ia = Ia > 0.f ? Ia : 0.f;
    float Ic = fmaf(bf2f(bb[(size_t)(i00 + dx) * 64]), sa, sb);      Ic = Ic > 0.f ? Ic : 0.f;
    float Ib = fmaf(bf2f(bb[(size_t)(i00 + dy) * 64]), sa, sb);      Ib = Ib > 0.f ? Ib : 0.f;
    float Id = fmaf(bf2f(bb[(size_t)(i00 + dy + dx) * 64]), sa, sb); Id = Id > 0.f ? Id : 0.f;
    float f = wa * Ia + wb * Ib + wc * Ic + wd * Id;
    pf[(size_t)p * 64 + lane] = f2bf(f);
  }
}

// ---------------- K4b: point heads (cls/offset/embedding), vectorized pf reads ----------------
__global__ void k_heads(const unsigned short* __restrict__ pf,
                        const float* __restrict__ wseg, const float* __restrict__ bseg,
                        const float* __restrict__ wreg, const float* __restrict__ breg,
                        const float* __restrict__ wemb, const float* __restrict__ bemb,
                        float* __restrict__ ocls, float* __restrict__ ooff, float* __restrict__ oemb) {
  const int p = blockIdx.x * 256 + threadIdx.x;
  if (p >= NPTS) return;
  float a0 = bseg[0], a1 = bseg[1], a2 = bseg[2];
  float r0 = breg[0], r1 = breg[1], r2 = breg[2];
  float e0 = bemb[0], e1 = bemb[1];
  const u16x8* q = (const u16x8*)(pf + (size_t)p * 64);
#pragma unroll
  for (int g = 0; g < 8; ++g) {
    u16x8 v8 = q[g];
#pragma unroll
    for (int k = 0; k < 8; ++k) {
      int kk = g * 8 + k;
      float v = bf2f(v8[k]);
      a0 = fmaf(v, wseg[kk * 3 + 0], a0);
      a1 = fmaf(v, wseg[kk * 3 + 1], a1);
      a2 = fmaf(v, wseg[kk * 3 + 2], a2);
      r0 = fmaf(v, wreg[kk * 3 + 0], r0);
      r1 = fmaf(v, wreg[kk * 3 + 1], r1);
      r2 = fmaf(v, wreg[kk * 3 + 2], r2);
      e0 = fmaf(v, wemb[kk * 2 + 0], e0);
      e1 = fmaf(v, wemb[kk * 2 + 1], e1);
    }
  }
  ocls[p * 3 + 0] = a0; ocls[p * 3 + 1] = a1; ocls[p * 3 + 2] = a2;
  ooff[p * 3 + 0] = r0; ooff[p * 3 + 1] = r1; ooff[p * 3 + 2] = r2;
  oemb[p * 2 + 0] = e0; oemb[p * 2 + 1] = e1;
}

// ---------------- K5: LDS-privatized histogram + local rank (coalesced [blk][seg] writeback) ----------------
__global__ __launch_bounds__(256) void k_hist2(const float* __restrict__ pts,
                                               int* __restrict__ seg, int* __restrict__ rankp,
                                               int* __restrict__ bh) {
  __shared__ int lc[NSEG];
  const int t = threadIdx.x, blk = blockIdx.x;
  for (int i = t; i < NSEG; i += 256) lc[i] = 0;
  __syncthreads();
  const int p0 = blk * PPB;
  for (int i = t; i < PPB; i += 256) {
    int p = p0 + i;
    const float* pr = pts + (size_t)p * 9;
    int b = (int)pr[0];
    int sw = (int)pr[6];
    int ins = (int)pr[7];
    int s = (b * 64 + ins) * 10 + sw;
    seg[p] = s;
    rankp[p] = atomicAdd(&lc[s], 1);
  }
  __syncthreads();
  for (int i = t; i < NSEG; i += 256) bh[(size_t)blk * NSEG + i] = lc[i];
}

// ---------------- K6a: per-segment prefix across blocks (coalesced row sweeps) ----------------
__global__ void k_scan2a(const int* __restrict__ bh, int* __restrict__ basebk,
                         int* __restrict__ tot) {
  const int s = blockIdx.x * 256 + threadIdx.x;  // 0..2559
  int acc = 0;
  for (int b = 0; b < NBLK; ++b) {
    int v = bh[(size_t)b * NSEG + s];
    basebk[(size_t)b * NSEG + s] = acc;
    acc += v;
  }
  tot[s] = acc;
}

// ---------------- K6b: exclusive scan of segment totals ----------------
__global__ void k_scan2b(const int* __restrict__ tot, int* __restrict__ base,
                         int* __restrict__ cnt) {
  __shared__ int csum[256];
  const int t = threadIdx.x;
  int loc[10]; int run = 0;
#pragma unroll
  for (int k = 0; k < 10; ++k) { loc[k] = tot[t * 10 + k]; run += loc[k]; }
  csum[t] = run;
  __syncthreads();
  if (t == 0) {
    int a = 0;
    for (int i = 0; i < 256; ++i) { int v = csum[i]; csum[i] = a; a += v; }
  }
  __syncthreads();
  int acc = csum[t];
#pragma unroll
  for (int k = 0; k < 10; ++k) {
    int s = t * 10 + k;
    base[s] = acc; cnt[s] = loc[k];
    acc += loc[k];
  }
}

// ---------------- K7: atomic-free scatter ----------------
__global__ void k_scatter2(const int* __restrict__ seg, const int* __restrict__ rankp,
                           const int* __restrict__ base, const int* __restrict__ basebk,
                           int* __restrict__ order) {
  const int p = blockIdx.x * 256 + threadIdx.x;
  if (p < NPTS) {
    int s = seg[p];
    int blk = p / PPB;
    order[base[s] + basebk[(size_t)blk * NSEG + s] + rankp[p]] = p;
  }
}

// ---------------- K8: per-segment centroid + shape max + feat max (8 waves) ----------------
__global__ __launch_bounds__(512) void k_seg(const int* __restrict__ cnt, const int* __restrict__ base,
                      const int* __restrict__ order, const float* __restrict__ pts,
                      const unsigned short* __restrict__ pf,
                      const float* __restrict__ wsh, const float* __restrict__ bsh,
                      float* __restrict__ lf, float* __restrict__ centroid,
                      int* __restrict__ nonempty) {
  const int s = blockIdx.x;
  const int t = threadIdx.x, lane = t & 63, wv = t >> 6;
  const int n = cnt[s], bs = base[s];
  float sx = 0.f, sy = 0.f, sz = 0.f;
  for (int i = t; i < n; i += 512) {
    int p = order[bs + i];
    const float* pr = pts + (size_t)p * 9;
    sx += pr[1]; sy += pr[2]; sz += pr[3];
  }
#pragma unroll
  for (int m = 32; m > 0; m >>= 1) {
    sx += __shfl_xor(sx, m); sy += __shfl_xor(sy, m); sz += __shfl_xor(sz, m);
  }
  __shared__ float red[3][8];
  __shared__ float csh[3];
  if (lane == 0) { red[0][wv] = sx; red[1][wv] = sy; red[2][wv] = sz; }
  __syncthreads();
  if (t == 0) {
    float dn = (float)max(n, 1);
    float ax = 0.f, ay = 0.f, az = 0.f;
#pragma unroll
    for (int k = 0; k < 8; ++k) { ax += red[0][k]; ay += red[1][k]; az += red[2][k]; }
    csh[0] = ax / dn; csh[1] = ay / dn; csh[2] = az / dn;
  }
  __syncthreads();
  const float cx = csh[0], cy = csh[1], cz = csh[2];
  const float w0 = wsh[lane], w1 = wsh[64 + lane], w2 = wsh[128 + lane], bb = bsh[lane];
  float smax = -INFINITY, lmax = -INFINITY;
  for (int i = wv; i < n; i += 8) {
    int p = order[bs + i];
    const float* pr = pts + (size_t)p * 9;
    float sv = fmaf(pr[1] - cx, w0, fmaf(pr[2] - cy, w1, fmaf(pr[3] - cz, w2, bb)));
    smax = fmaxf(smax, sv);
    lmax = fmaxf(lmax, bf2f(pf[(size_t)p * 64 + lane]));
  }
  __shared__ float rs[8][64], rl[8][64];
  rs[wv][lane] = smax; rl[wv][lane] = lmax;
  __syncthreads();
  if (wv == 0) {
#pragma unroll
    for (int k = 1; k < 8; ++k) {
      smax = fmaxf(smax, rs[k][lane]);
      lmax = fmaxf(lmax, rl[k][lane]);
    }
    bool ne = n > 0;
    lf[s * 64 + lane] = (ne ? lmax : 0.f) + (ne ? smax : 0.f);
    if (lane == 0) {
      nonempty[s] = ne ? 1 : 0;
      centroid[s * 3 + 0] = cx; centroid[s * 3 + 1] = cy; centroid[s * 3 + 2] = cz;
    }
  }
}

// ---------------- K9: per-instance globals + sweep min/max + inst_mos ----------------
__global__ void k_glob(const float* __restrict__ lf, const int* __restrict__ ne,
                       const float* __restrict__ centroid,
                       const float* __restrict__ wmos, const float* __restrict__ bmos,
                       float* __restrict__ gf, float* __restrict__ tc, float* __restrict__ ic,
                       float* __restrict__ omos) {
  const int i = blockIdx.x;
  const int t = threadIdx.x; // 64 threads
  float g = -INFINITY;
  int maxsw = -1, minsw = 10;
  bool any = false;
#pragma unroll
  for (int s = 0; s < 10; ++s) {
    int idx = i * 10 + s;
    bool e = ne[idx] != 0;
    float v = lf[idx * 64 + t];
    g = fmaxf(g, e ? v : -INFINITY);
    if (e) { any = true; maxsw = s; minsw = min(minsw, s); }
  }
  float gv = any ? g : 0.f;
  gf[i * 64 + t] = gv;
  int idxmax = min(max(i * 10 + maxsw, 0), NSEG - 1);
  int idxmin = min(max(i * 10 + minsw, 0), NSEG - 1);
  float tcx = centroid[idxmax * 3 + 0], tcy = centroid[idxmax * 3 + 1], tcz = centroid[idxmax * 3 + 2];
  float icx = centroid[idxmin * 3 + 0], icy = centroid[idxmin * 3 + 1], icz = centroid[idxmin * 3 + 2];
  if (t == 0) {
    tc[i * 3 + 0] = tcx; tc[i * 3 + 1] = tcy; tc[i * 3 + 2] = tcz;
    ic[i * 3 + 0] = icx; ic[i * 3 + 1] = icy; ic[i * 3 + 2] = icz;
  }
  float r = gv * wmos[t];
#pragma unroll
  for (int m = 32; m > 0; m >>= 1) r += __shfl_xor(r, m);
  if (t == 0) {
    r += icx * wmos[64] + icy * wmos[65] + icz * wmos[66];
    r += tcx * wmos[67] + tcy * wmos[68] + tcz * wmos[69];
    omos[i] = r + bmos[0];
  }
}

// ---------------- K10: locals_tf = locals_cat(134) @ w_tf(134x7) ----------------
__global__ void k_tf(const float* __restrict__ lf, const float* __restrict__ gf,
                     const float* __restrict__ centroid, const float* __restrict__ tc,
                     const float* __restrict__ wtf, const float* __restrict__ btf,
                     float* __restrict__ otf) {
  const int r = blockIdx.x * 256 + threadIdx.x;
  if (r >= NSEG) return;
  const int i = r / 10;
  float acc[7];
#pragma unroll
  for (int j = 0; j < 7; ++j) acc[j] = btf[j];
  for (int k = 0; k < 64; ++k) {
    float v = lf[r * 64 + k];
#pragma unroll
    for (int j = 0; j < 7; ++j) acc[j] = fmaf(v, wtf[k * 7 + j], acc[j]);
  }
  for (int k = 0; k < 64; ++k) {
    float v = gf[i * 64 + k];
#pragma unroll
    for (int j = 0; j < 7; ++j) acc[j] = fmaf(v, wtf[(64 + k) * 7 + j], acc[j]);
  }
#pragma unroll
  for (int c = 0; c < 3; ++c) {
    float v = centroid[r * 3 + c];
#pragma unroll
    for (int j = 0; j < 7; ++j) acc[j] = fmaf(v, wtf[(128 + c) * 7 + j], acc[j]);
  }
#pragma unroll
  for (int c = 0; c < 3; ++c) {
    float v = tc[i * 3 + c];
#pragma unroll
    for (int j = 0; j < 7; ++j) acc[j] = fmaf(v, wtf[(131 + c) * 7 + j], acc[j]);
  }
#pragma unroll
  for (int j = 0; j < 7; ++j) otf[r * 7 + j] = acc[j];
}

extern "C" void kernel_launch(void* const* d_in, const int* in_sizes, int n_in,
                              void* d_out, int out_size, void* d_ws, size_t ws_size,
                              hipStream_t stream) {
  const float* pts   = (const float*)d_in[0];
  const float* x     = (const float*)d_in[1];
  const float* convw = (const float*)d_in[2];
  const float* gamma = (const float*)d_in[3];
  const float* beta  = (const float*)d_in[4];
  const float* wseg  = (const float*)d_in[5];
  const float* bseg  = (const float*)d_in[6];
  const float* wreg  = (const float*)d_in[7];
  const float* breg  = (const float*)d_in[8];
  const float* wemb  = (const float*)d_in[9];
  const float* bemb  = (const float*)d_in[10];
  const float* wsh   = (const float*)d_in[11];
  const float* bsh   = (const float*)d_in[12];
  const float* wtf   = (const float*)d_in[13];
  const float* btf   = (const float*)d_in[14];
  const float* wmos  = (const float*)d_in[15];
  const float* bmos  = (const float*)d_in[16];

  float* out = (float*)d_out;
  float* o_cls = out;                 // 400000 x 3
  float* o_off = out + 1200000;       // 400000 x 3
  float* o_emb = out + 2400000;       // 400000 x 2
  float* o_tf  = out + 3200000;       // 2560 x 7
  float* o_mos = out + 3217920;       // 256 x 1

  char* wsp = (char*)d_ws;
  size_t off = 0;
  auto alloc = [&](size_t bytes) -> void* {
    void* p = wsp + off;
    off = (off + bytes + 255) & ~(size_t)255;
    return p;
  };
  // xt dead after conv -> pf aliases it.
  unsigned short* xt   = (unsigned short*)alloc((size_t)4 * WID * WID * NCI * 2); // 66.4 MB
  unsigned short* pf   = xt;
  unsigned short* wbuf = (unsigned short*)alloc((size_t)9 * 8 * 64 * 32 * 2);
  unsigned short* y    = (unsigned short*)alloc((size_t)4 * HW * 64 * 2);         // 16.6 MB
  int*   seg      = (int*)alloc((size_t)NPTS * 4);
  int*   rankp    = (int*)alloc((size_t)NPTS * 4);
  int*   order    = (int*)alloc((size_t)NPTS * 4);
  int*   bh       = (int*)alloc((size_t)NBLK * NSEG * 4);   // 5.12 MB, [blk][seg]
  int*   basebk   = (int*)alloc((size_t)NBLK * NSEG * 4);   // 5.12 MB, [blk][seg]
  int*   tot      = (int*)alloc(NSEG * 4);
  int*   cnt      = (int*)alloc(NSEG * 4);
  int*   base     = (int*)alloc(NSEG * 4);
  float* part     = (float*)alloc((size_t)720 * 64 * 2 * 4);
  float* ab       = (float*)alloc(64 * 2 * 4);
  float* centroid = (float*)alloc(NSEG * 3 * 4);
  float* lf       = (float*)alloc(NSEG * 64 * 4);
  int*   nonem    = (int*)alloc(NSEG * 4);
  float* gf       = (float*)alloc(NINST * 64 * 4);
  float* tc       = (float*)alloc(NINST * 3 * 4);
  float* ic       = (float*)alloc(NINST * 3 * 4);
  float* zbuf     = (float*)alloc(2048);
  (void)ws_size; (void)n_in; (void)in_sizes; (void)out_size;

  hipMemsetAsync(zbuf, 0, 2048, stream);

  k_hist2<<<NBLK, 256, 0, stream>>>(pts, seg, rankp, bh);
  k_scan2a<<<10, 256, 0, stream>>>(bh, basebk, tot);
  k_scan2b<<<1, 256, 0, stream>>>(tot, base, cnt);
  k_scatter2<<<(NPTS + 255) / 256, 256, 0, stream>>>(seg, rankp, base, basebk, order);
  k_transpose<<<dim3(12, WID, 4), 256, 0, stream>>>(x, xt);
  k_wreorg<<<576, 256, 0, stream>>>(convw, wbuf);
  k_conv_mfma<<<720, 256, 0, stream>>>(xt, wbuf, zbuf, y, part);
  k_bnparams<<<1, 64, 0, stream>>>(part, gamma, beta, ab);
  k_points<<<12500, 256, 0, stream>>>(pts, y, ab, pf);
  k_heads<<<(NPTS + 255) / 256, 256, 0, stream>>>(pf, wseg, bseg, wreg, breg, wemb, bemb,
                                                  o_cls, o_off, o_emb);
  k_seg<<<NSEG, 512, 0, stream>>>(cnt, base, order, pts, pf, wsh, bsh, lf, centroid, nonem);
  k_glob<<<NINST, 64, 0, stream>>>(lf, nonem, centroid, wmos, bmos, gf, tc, ic, o_mos);
  k_tf<<<(NSEG + 255) / 256, 256, 0, stream>>>(lf, gf, centroid, tc, wtf, btf, o_tf);
}